// Round 3
// baseline (478.459 us; speedup 1.0000x reference)
//
#include <hip/hip_runtime.h>

typedef __attribute__((ext_vector_type(8))) short short8;
typedef __attribute__((ext_vector_type(4))) float f32x4;

constexpr int L = 1024, C = 256, F = 256;
constexpr int NIMG = 256;          // B*M
constexpr int LOUT = 1022;         // L - K + 1
constexpr long MAXROW = (long)NIMG * L - 1;

__device__ inline unsigned short f2bf(float f) {
  union { float f; unsigned u; } v; v.f = f;
  return (unsigned short)((v.u + 0x7FFFu + ((v.u >> 16) & 1u)) >> 16);  // RNE
}

__device__ inline void g2l16(const unsigned short* g, unsigned short* l) {
  __builtin_amdgcn_global_load_lds(
      (const __attribute__((address_space(1))) unsigned int*)g,
      (__attribute__((address_space(3))) unsigned int*)l, 16, 0, 0);
}

// Pre-pass: W (3,256,256) fp32 -> Wt bf16, layout [tile(slab*3+k)][f(256)][kp(32)]
// so each main-kernel B tile (256x32 bf16 = 16 KB) is one contiguous chunk.
__global__ void wprep(const float* __restrict__ W, unsigned short* __restrict__ Wt) {
  int tid = blockIdx.x * 256 + threadIdx.x;       // exactly 768*256 threads
  int kc = tid >> 8, f = tid & 255;               // coalesced read of W[tid]
  int k = kc >> 8, c = kc & 255;
  int slab = c >> 5, kp = c & 31;
  Wt[(size_t)(((slab * 3 + k) * 256 + f) * 32 + kp)] = f2bf(W[tid]);
}

// 512-thread block computes 256(L)x256(F); wave tile 128x64 (af[8], acc[8][4])
// halves LDS-read bytes per MAC in M (LDS-BW was the R2 limiter).
// Schedule (unchanged from R2): 1 raw barrier/step, counted vmcnt (no full
// drain mid-loop), Bs tri-buffered dist-2 (tile t -> Bs[t%3] == Bs[k]),
// A reg-issued at k0, packed+written at k2.
__global__ __launch_bounds__(512, 2) void conv_mfma(
    const float* __restrict__ x, const unsigned short* __restrict__ Wt,
    const float* __restrict__ bias, float* __restrict__ y)
{
  __shared__ __align__(16) unsigned short As[2][1032 * 8];  // 2 x 16512 B (258 rows x 32 bf16)
  __shared__ __align__(16) unsigned short Bs[3][512 * 16];  // 3 x 16384 B (256 f x 32 bf16)

  const int bid = blockIdx.x;       // 1024 blocks
  const int mt  = bid & 3;          // 4 m-tiles of 256 rows over Lout=1022
  const int img = bid >> 2;         // 256 images
  const int l0  = mt * 256;

  const int tid  = threadIdx.x;
  const int lane = tid & 63;
  const int wv   = tid >> 6;        // 8 waves: 2(M) x 4(F); wave tile 128 x 64
  const int wr   = wv >> 2;
  const int wc   = wv & 3;
  const int lr   = lane & 15;
  const int quad = lane >> 4;

  f32x4 acc[8][4] = {};             // 128 VGPRs
  float4 av[2][2];                  // A chunks tid, tid+512 (8 fp32 each)
  float4 avt[2];                    // tail chunks 1024..1031 (tid < 8)

  const long gb = (long)img * L + l0;

  auto issue_A = [&](int slab) {    // global -> regs, rows 0..257 of slab (fp32)
    const int cb = slab * 32;
    long g0 = gb + (tid >> 2);        if (g0 > MAXROW) g0 = MAXROW;  // clamped rows
    long g1 = gb + 128 + (tid >> 2);  if (g1 > MAXROW) g1 = MAXROW;  // feed only
    const float* p0 = x + g0 * C + cb + (tid & 3) * 8;               // masked outputs
    const float* p1 = x + g1 * C + cb + (tid & 3) * 8;
    av[0][0] = *(const float4*)p0; av[0][1] = *(const float4*)(p0 + 4);
    av[1][0] = *(const float4*)p1; av[1][1] = *(const float4*)(p1 + 4);
    if (tid < 8) {
      long g2 = gb + 256 + (tid >> 2); if (g2 > MAXROW) g2 = MAXROW;
      const float* p2 = x + g2 * C + cb + (tid & 3) * 8;
      avt[0] = *(const float4*)p2; avt[1] = *(const float4*)(p2 + 4);
    }
  };

  auto pack8 = [&](float4 a, float4 b) {
    short8 r;
    r[0] = (short)f2bf(a.x); r[1] = (short)f2bf(a.y);
    r[2] = (short)f2bf(a.z); r[3] = (short)f2bf(a.w);
    r[4] = (short)f2bf(b.x); r[5] = (short)f2bf(b.y);
    r[6] = (short)f2bf(b.z); r[7] = (short)f2bf(b.w);
    return r;
  };

  auto write_A = [&](int ab2) {     // 1032 chunks of 16 B, contiguous -> balanced
    *(short8*)(As[ab2] + (size_t)tid * 8)         = pack8(av[0][0], av[0][1]);
    *(short8*)(As[ab2] + (size_t)(tid + 512) * 8) = pack8(av[1][0], av[1][1]);
    if (tid < 8)
      *(short8*)(As[ab2] + (size_t)(1024 + tid) * 8) = pack8(avt[0], avt[1]);
  };

  auto stage_B = [&](int tile, int bb) {  // 16 KB contiguous, 2 g2l16/thread (exact)
    const unsigned short* bsrc = Wt + (size_t)tile * 8192;
    g2l16(bsrc + (size_t)tid * 8,         Bs[bb] + (size_t)tid * 8);
    g2l16(bsrc + (size_t)(tid + 512) * 8, Bs[bb] + (size_t)(tid + 512) * 8);
  };

  // ---- prologue: av(slab0) [4 loads, wave0 6], B0 [2], B1 [2] in flight;
  // write_A's av dependency makes the compiler drain av (vmcnt(4)), leaving B0,B1.
  issue_A(0);
  stage_B(0, 0);
  stage_B(1, 1);
  write_A(0);

  for (int slab = 0; slab < 8; ++slab) {
    const int ab = slab & 1;
#pragma unroll
    for (int k = 0; k < 3; ++k) {
      // Top-of-step wait: tile t (t = slab*3+k, staged at t-2) must be done,
      // plus (k0) As ds_writes visible. FIFO per wave (issue order: stage_B
      // then av at k0; av consumed by write_A at k2):
      //  k0-top: flight = B(t)2, B(t+1)2           -> vmcnt(2) lgkm(0)
      //  k1-top: flight = B(t)2, B(t+1)2, av4      -> vmcnt(6) (drains B(t))
      //  k2-top: flight = B(t)2, av4, B(t+1)2      -> vmcnt(6) (drains B(t))
      //  (wave0 has 6 av loads; same counts drain its B(t) too, only stricter)
      //  slab==7 (no av): 2+lgkm0 / 2 / 0
      if (slab < 7) {
        if (k == 0)      asm volatile("s_waitcnt vmcnt(2) lgkmcnt(0)" ::: "memory");
        else             asm volatile("s_waitcnt vmcnt(6)" ::: "memory");
      } else {
        if (k == 0)      asm volatile("s_waitcnt vmcnt(2) lgkmcnt(0)" ::: "memory");
        else if (k == 1) asm volatile("s_waitcnt vmcnt(2)" ::: "memory");
        else             asm volatile("s_waitcnt vmcnt(0)" ::: "memory");
      }
      __builtin_amdgcn_s_barrier();
      __builtin_amdgcn_sched_barrier(0);

      const int t = slab * 3 + k;
      if (t < 22) stage_B(t + 2, (k + 2) % 3);      // dist-2; buf idx compile-time
      if (k == 0 && slab < 7) issue_A(slab + 1);    // 2-step reg cover

      short8 af[8], bf[4];
#pragma unroll
      for (int mi = 0; mi < 8; ++mi)                // A[m=lr][kk=quad*8+j], +k shift
        af[mi] = *(const short8*)(As[ab] + (wr * 128 + mi * 16 + lr + k) * 32 + quad * 8);
#pragma unroll
      for (int ni = 0; ni < 4; ++ni)                // B stored [f][kk]
        bf[ni] = *(const short8*)(Bs[k] + (wc * 64 + ni * 16 + lr) * 32 + quad * 8);

      __builtin_amdgcn_s_setprio(1);
#pragma unroll
      for (int mi = 0; mi < 8; ++mi)
#pragma unroll
        for (int ni = 0; ni < 4; ++ni)
          acc[mi][ni] = __builtin_amdgcn_mfma_f32_16x16x32_bf16(af[mi], bf[ni], acc[mi][ni], 0, 0, 0);
      __builtin_amdgcn_s_setprio(0);

      if (k == 2 && slab < 7) write_A(ab ^ 1);      // pack next slab's A (other buffer)
    }
  }

  // Epilogue: C/D layout col=lane&15, row=quad*4+reg (m89/m91-verified)
  float bv[4];
#pragma unroll
  for (int ni = 0; ni < 4; ++ni)
    bv[ni] = bias[wc * 64 + ni * 16 + lr];

#pragma unroll
  for (int mi = 0; mi < 8; ++mi) {
#pragma unroll
    for (int r = 0; r < 4; ++r) {
      const int lrow = l0 + wr * 128 + mi * 16 + quad * 4 + r;
      if (lrow < LOUT) {
        float* yp = y + ((size_t)img * LOUT + lrow) * F + wc * 64 + lr;
#pragma unroll
        for (int ni = 0; ni < 4; ++ni)
          yp[ni * 16] = acc[mi][ni][r] + bv[ni];
      }
    }
  }
}

extern "C" void kernel_launch(void* const* d_in, const int* in_sizes, int n_in,
                              void* d_out, int out_size, void* d_ws, size_t ws_size,
                              hipStream_t stream) {
  const float* x = (const float*)d_in[0];   // (8,32,1024,256) fp32
  const float* W = (const float*)d_in[1];   // (3,256,256) fp32
  const float* b = (const float*)d_in[2];   // (256,) fp32
  float* y = (float*)d_out;                 // (8,32,1022,256) fp32
  unsigned short* Wt = (unsigned short*)d_ws;  // 3*256*256*2 = 393,216 B

  wprep<<<768, 256, 0, stream>>>(W, Wt);
  conv_mfma<<<NIMG * 4, 512, 0, stream>>>(x, Wt, b, y);
}